// Round 5
// baseline (119.020 us; speedup 1.0000x reference)
//
#include <hip/hip_runtime.h>
#include <math.h>

typedef unsigned short u16;
typedef unsigned int u32;
typedef __attribute__((ext_vector_type(8))) short bf16x8;
typedef __attribute__((ext_vector_type(4))) float f32x4;

// ---------------- bf16 helpers (manual RNE; inputs are finite) ----------------
__device__ __forceinline__ u16 f2bf(float x) {
    u32 b = __builtin_bit_cast(u32, x);
    b += 0x7FFFu + ((b >> 16) & 1u);
    return (u16)(b >> 16);
}
__device__ __forceinline__ float bf2f(u16 u) {
    u32 b = ((u32)u) << 16;
    return __builtin_bit_cast(float, b);
}

// Swizzled tiled plane address, in 16-byte units.
// Plane layout: [row/128][c/64] tiles of 1024 units;
// unit-in-tile = (row&127)*8 + (slot ^ (row&7)), slot = (c&63)>>3.
// XOR keeps ds_read_b128 fragment reads bank-conflict-free while the tile is
// copied linearly into LDS (T2 via pre-swizzled global, m173 pattern).
__device__ __forceinline__ size_t sw_unit(int row, int c, int CC) {
    int slot = (c & 63) >> 3;
    return ((size_t)((row >> 7) * CC + (c >> 6)) << 10)
         + (size_t)((row & 127) << 3) + (size_t)(slot ^ (row & 7));
}

// ---------------------------------------------------------------------------
// prep: convert+transpose activations / convert weights into swizzled hi/lo
// bf16 planes.
// ---------------------------------------------------------------------------
__device__ void prep_x(const float* __restrict__ X, int C, int HW, int bl, int PT,
                       u16* __restrict__ dh, u16* __restrict__ dl) {
    __shared__ float Xt[64][65];
    const int t = threadIdx.x;
    const int pt = bl % PT, ct = bl / PT;
    const int p0 = pt * 64, c0 = ct * 64;
    const int b = p0 / HW, hw0 = p0 % HW;
    #pragma unroll
    for (int i = 0; i < 16; i++) {
        int r = (t >> 6) + i * 4;
        Xt[r][t & 63] = X[(size_t)(b * C + c0 + r) * HW + hw0 + (t & 63)];
    }
    __syncthreads();
    const int CC = C >> 6;
    #pragma unroll
    for (int it = 0; it < 2; it++) {
        int id = t + it * 256;
        int px = id >> 3, sl = id & 7;
        bf16x8 hv, lv;
        #pragma unroll
        for (int j = 0; j < 8; j++) {
            float x = Xt[sl * 8 + j][px];
            u16 h = f2bf(x);
            hv[j] = (short)h;
            lv[j] = (short)f2bf(x - bf2f(h));
        }
        size_t unit = sw_unit(p0 + px, c0 + sl * 8, CC);
        *(bf16x8*)(dh + unit * 8) = hv;
        *(bf16x8*)(dl + unit * 8) = lv;
    }
}

__device__ void prep_w(const float* __restrict__ W, int C, int bl,
                       u16* __restrict__ dh, u16* __restrict__ dl) {
    const int t = threadIdx.x;
    const int ot = bl & 3, cc = bl >> 2;
    const int o0 = ot * 64, c0 = cc * 64;
    const int CC = C >> 6;
    #pragma unroll
    for (int it = 0; it < 2; it++) {
        int id = t + it * 256;
        int ol = id >> 3, sl = id & 7;
        int o = o0 + ol, c = c0 + sl * 8;
        const float* wp = W + (size_t)o * C + c;
        float4 a = *(const float4*)wp;
        float4 b2 = *(const float4*)(wp + 4);
        float xs[8] = {a.x, a.y, a.z, a.w, b2.x, b2.y, b2.z, b2.w};
        bf16x8 hv, lv;
        #pragma unroll
        for (int j = 0; j < 8; j++) {
            u16 h = f2bf(xs[j]);
            hv[j] = (short)h;
            lv[j] = (short)f2bf(xs[j] - bf2f(h));
        }
        size_t unit = sw_unit(o, c, CC);
        *(bf16x8*)(dh + unit * 8) = hv;
        *(bf16x8*)(dl + unit * 8) = lv;
    }
}

// W plane offsets in u16 units inside the combined Whi/Wlo buffers
#define OFF_WQ 0
#define OFF_WK0 65536
#define OFF_WV0 163840
#define OFF_WK1 262144
#define OFF_WV1 458752
#define OFF_WFUSE 655360

__global__ __launch_bounds__(256) void prep_k(
    const float* __restrict__ query, const float* __restrict__ mem0, const float* __restrict__ mem1,
    const float* __restrict__ Wq, const float* __restrict__ Wk0, const float* __restrict__ Wv0,
    const float* __restrict__ Wk1, const float* __restrict__ Wv1, const float* __restrict__ Wfuse,
    u16* Xq_hi, u16* Xq_lo, u16* Xm0_hi, u16* Xm0_lo, u16* Xm1_hi, u16* Xm1_lo,
    u16* Whi, u16* Wlo)
{
    const int bx = blockIdx.x;
    if (bx < 512)      prep_x(query, 256, 4096, bx,       128, Xq_hi, Xq_lo);
    else if (bx < 704) prep_x(mem0,  384, 1024, bx - 512,  32, Xm0_hi, Xm0_lo);
    else if (bx < 800) prep_x(mem1,  768,  256, bx - 704,   8, Xm1_hi, Xm1_lo);
    else {
        int r = bx - 800;
        if (r < 16)       prep_w(Wq,    256, r,       Whi + OFF_WQ,    Wlo + OFF_WQ);
        else if (r < 40)  prep_w(Wk0,   384, r - 16,  Whi + OFF_WK0,   Wlo + OFF_WK0);
        else if (r < 64)  prep_w(Wv0,   384, r - 40,  Whi + OFF_WV0,   Wlo + OFF_WV0);
        else if (r < 112) prep_w(Wk1,   768, r - 64,  Whi + OFF_WK1,   Wlo + OFF_WK1);
        else if (r < 160) prep_w(Wv1,   768, r - 112, Whi + OFF_WV1,   Wlo + OFF_WV1);
        else              prep_w(Wfuse, 512, r - 160, Whi + OFF_WFUSE, Wlo + OFF_WFUSE);
    }
}

// ---------------------------------------------------------------------------
// Split-bf16 MFMA GEMM core. D[r][c] = sum_k A[r][k]*B[k][c] (+bias), with
// A,B given as swizzled hi/lo bf16 planes ([row][k] tiles). Block = 128x128,
// 4 waves of 64x64 (4x4 16x16 D-tiles each), KC=64, single-buffered LDS.
// Staging: plain register copy (global bf16x8 load -> LDS store), linear —
// NO global_load_lds builtin (clang-22 segfaulted on it in R2).
// BPL=2: 3-term split (AhiBhi+AloBhi+AhiBlo). BPL=1: B has hi plane only.
// OUT16=true : Y is u16* bf16 pixel-major [row][256].
// OUT16=false: Y is float* channel-major out [2][256][4096].
// ---------------------------------------------------------------------------
template<int BPL, bool OUT16>
__device__ __forceinline__ void gemm_core(
    const u16* __restrict__ Ahi, const u16* __restrict__ Alo,
    const u16* __restrict__ Bhi, const u16* __restrict__ Blo,
    const float* __restrict__ bias, void* __restrict__ Y,
    int CC, int am, int bn, u16* smem)
{
    constexpr int PL = 2 + BPL;
    const int t = threadIdx.x, lane = t & 63, w = t >> 6;
    const int wr = w >> 1, wc = w & 1;

    f32x4 acc[4][4];
    #pragma unroll
    for (int a = 0; a < 4; a++)
        #pragma unroll
        for (int b = 0; b < 4; b++)
            acc[a][b] = (f32x4){0.f, 0.f, 0.f, 0.f};

    for (int ck = 0; ck < CC; ck++) {
        // ---- stage chunk: linear plane copy, 16B per thread per pass ----
        const size_t aoff = ((size_t)(am * CC + ck)) << 13;  // 8192 u16 per tile
        const size_t boff = ((size_t)(bn * CC + ck)) << 13;
        bf16x8 stg[PL][4];
        #pragma unroll
        for (int it = 0; it < 4; it++) {
            const size_t o = (size_t)(t + it * 256) * 8;
            stg[0][it] = *(const bf16x8*)(Ahi + aoff + o);
            stg[1][it] = *(const bf16x8*)(Alo + aoff + o);
            stg[2][it] = *(const bf16x8*)(Bhi + boff + o);
            if (BPL == 2) stg[3][it] = *(const bf16x8*)(Blo + boff + o);
        }
        __syncthreads();   // previous chunk's compute done before overwrite
        #pragma unroll
        for (int p = 0; p < PL; p++)
            #pragma unroll
            for (int it = 0; it < 4; it++)
                *(bf16x8*)(smem + p * 8192 + (size_t)(t + it * 256) * 8) = stg[p][it];
        __syncthreads();   // chunk landed in LDS

        // ---- compute: 2 k-steps of 32 ----
        #pragma unroll
        for (int kk = 0; kk < 2; kk++) {
            bf16x8 ah[4], al[4], bh[4], bl[4];
            #pragma unroll
            for (int tr = 0; tr < 4; tr++) {
                int row = wr * 64 + tr * 16 + (lane & 15);
                int off = row * 64 + (((kk * 4 + (lane >> 4)) ^ (row & 7)) << 3);
                ah[tr] = *(const bf16x8*)(smem + off);
                al[tr] = *(const bf16x8*)(smem + 8192 + off);
            }
            #pragma unroll
            for (int tc = 0; tc < 4; tc++) {
                int row = wc * 64 + tc * 16 + (lane & 15);
                int off = row * 64 + (((kk * 4 + (lane >> 4)) ^ (row & 7)) << 3);
                bh[tc] = *(const bf16x8*)(smem + 16384 + off);
                if (BPL == 2) bl[tc] = *(const bf16x8*)(smem + 24576 + off);
            }
            #pragma unroll
            for (int tr = 0; tr < 4; tr++)
                #pragma unroll
                for (int tc = 0; tc < 4; tc++) {
                    acc[tr][tc] = __builtin_amdgcn_mfma_f32_16x16x32_bf16(ah[tr], bh[tc], acc[tr][tc], 0, 0, 0);
                    acc[tr][tc] = __builtin_amdgcn_mfma_f32_16x16x32_bf16(al[tr], bh[tc], acc[tr][tc], 0, 0, 0);
                    if (BPL == 2)
                        acc[tr][tc] = __builtin_amdgcn_mfma_f32_16x16x32_bf16(ah[tr], bl[tc], acc[tr][tc], 0, 0, 0);
                }
        }
    }

    // ---- epilogue: D row = (lane>>4)*4+i, col = lane&15 (m89-verified) ----
    if (OUT16) {
        u16* Y16 = (u16*)Y;
        float bv[4];
        #pragma unroll
        for (int tc = 0; tc < 4; tc++)
            bv[tc] = bias[bn * 128 + wc * 64 + tc * 16 + (lane & 15)];
        #pragma unroll
        for (int tr = 0; tr < 4; tr++) {
            #pragma unroll
            for (int i = 0; i < 4; i++) {
                int rp = am * 128 + wr * 64 + tr * 16 + ((lane >> 4) << 2) + i;
                u16* yr = Y16 + (size_t)rp * 256 + bn * 128 + wc * 64 + (lane & 15);
                #pragma unroll
                for (int tc = 0; tc < 4; tc++)
                    yr[tc * 16] = f2bf(acc[tr][tc][i] + bv[tc]);
            }
        }
    } else {
        float* Yf = (float*)Y;
        #pragma unroll
        for (int tr = 0; tr < 4; tr++) {
            #pragma unroll
            for (int i = 0; i < 4; i++) {
                int o = am * 128 + wr * 64 + tr * 16 + ((lane >> 4) << 2) + i;
                float bv = bias[o];
                #pragma unroll
                for (int tc = 0; tc < 4; tc++) {
                    int pcol = bn * 128 + wc * 64 + tc * 16 + (lane & 15);
                    Yf[(size_t)((pcol >> 12) * 256 + o) * 4096 + (pcol & 4095)] = acc[tr][tc][i] + bv;
                }
            }
        }
    }
}

// proj: q / k0 / v0 / k1 / v1 in one dispatch (208 blocks); bf16 outputs
__global__ __launch_bounds__(256) void projmm_k(
    const u16* __restrict__ Xq_hi, const u16* __restrict__ Xq_lo,
    const u16* __restrict__ Xm0_hi, const u16* __restrict__ Xm0_lo,
    const u16* __restrict__ Xm1_hi, const u16* __restrict__ Xm1_lo,
    const u16* __restrict__ Whi, const u16* __restrict__ Wlo,
    const float* __restrict__ bq, const float* __restrict__ bk0, const float* __restrict__ bv0,
    const float* __restrict__ bk1, const float* __restrict__ bv1,
    u16* qT, u16* k0T, u16* v0T, u16* k1T, u16* v1T)
{
    __shared__ u16 smem[32768];   // 64 KB
    const int bx = blockIdx.x;
    const u16 *Ah, *Al, *Bh, *Bl; const float* bias; u16* Y;
    int CC, am, bn;
    if (bx < 128) {
        am = bx >> 1; bn = bx & 1; CC = 4;
        Ah = Xq_hi; Al = Xq_lo; Bh = Whi + OFF_WQ; Bl = Wlo + OFF_WQ; bias = bq; Y = qT;
    } else if (bx < 192) {
        int r = bx - 128; am = r >> 2; int bnn = r & 3; CC = 6;
        Ah = Xm0_hi; Al = Xm0_lo;
        if (bnn < 2) { Bh = Whi + OFF_WK0; Bl = Wlo + OFF_WK0; bias = bk0; Y = k0T; bn = bnn; }
        else         { Bh = Whi + OFF_WV0; Bl = Wlo + OFF_WV0; bias = bv0; Y = v0T; bn = bnn - 2; }
    } else {
        int r = bx - 192; am = r >> 2; int bnn = r & 3; CC = 12;
        Ah = Xm1_hi; Al = Xm1_lo;
        if (bnn < 2) { Bh = Whi + OFF_WK1; Bl = Wlo + OFF_WK1; bias = bk1; Y = k1T; bn = bnn; }
        else         { Bh = Whi + OFF_WV1; Bl = Wlo + OFF_WV1; bias = bv1; Y = v1T; bn = bnn - 2; }
    }
    gemm_core<2, true>(Ah, Al, Bh, Bl, bias, (void*)Y, CC, am, bn, smem);
}

// fuse: out = Wfuse * fused + bfuse (A = Wfuse rows, B = fused pixels), 128 blocks
__global__ __launch_bounds__(256) void fusemm_k(
    const u16* __restrict__ Whi, const u16* __restrict__ Wlo,
    const u16* __restrict__ fhi, const float* __restrict__ bfuse, float* out)
{
    __shared__ u16 smem[24576];   // 48 KB
    const int bx = blockIdx.x;
    gemm_core<1, false>(Whi + OFF_WFUSE, Wlo + OFF_WFUSE, fhi, (const u16*)nullptr,
                        bfuse, (void*)out, 8, bx & 1, bx >> 1, smem);
}

// ---------------------------------------------------------------------------
// Attention, 4-way neighbor-parallel: 4 lanes share one (b, head, q-pixel).
// Each lane online-softmaxes its neighbor subset (j = part, part+4, ...),
// the 4 partial states merge via a 2-round shfl_xor butterfly, and each lane
// writes its 8-channel slice of the output (static register indexing).
// q/k/v are bf16 pixel-major [p][256]; unpack via shift-only bit tricks.
// ---------------------------------------------------------------------------
template<int WS, int DIL, int SF, int HM, int WM>
__device__ __forceinline__ void attn_one4(
    const u16* __restrict__ qT, const u16* __restrict__ kT,
    const u16* __restrict__ vT, u16* __restrict__ fhi,
    int b, int n, int qy, int qx, int part, int s_off)
{
    const int p = (b * 64 + qy) * 64 + qx;

    float q[32];
    {
        const u16* qp = qT + (size_t)p * 256 + n * 32;
        #pragma unroll
        for (int i = 0; i < 4; i++) {
            uint4 wv = *(const uint4*)(qp + i * 8);
            u32 ws[4] = {wv.x, wv.y, wv.z, wv.w};
            #pragma unroll
            for (int j2 = 0; j2 < 4; j2++) {
                q[i*8 + 2*j2]     = __builtin_bit_cast(float, ws[j2] << 16);
                q[i*8 + 2*j2 + 1] = __builtin_bit_cast(float, ws[j2] & 0xFFFF0000u);
            }
        }
    }
    float o[32];
    #pragma unroll
    for (int d = 0; d < 32; d++) o[d] = 0.f;

    float m = -1e30f, l = 0.f;
    const int ay = qy / SF, ax = qx / SF;
    const float scale = 0.17677669529663687f;   // 32^-0.5

    for (int j = part; j < WS * WS; j += 4) {
        const int jy = j / WS, jx = j % WS;
        const int ym = ay + (jy - WS / 2) * DIL;
        const int xm = ax + (jx - WS / 2) * DIL;
        if (ym < 0 || ym >= HM || xm < 0 || xm >= WM) continue;
        const size_t base = (size_t)(((b * HM) + ym) * WM + xm) * 256 + n * 32;
        const u16* kp = kT + base;
        float dot = 0.f;
        #pragma unroll
        for (int i = 0; i < 4; i++) {
            uint4 wv = *(const uint4*)(kp + i * 8);
            u32 ws[4] = {wv.x, wv.y, wv.z, wv.w};
            #pragma unroll
            for (int j2 = 0; j2 < 4; j2++) {
                dot += q[i*8 + 2*j2]     * __builtin_bit_cast(float, ws[j2] << 16);
                dot += q[i*8 + 2*j2 + 1] * __builtin_bit_cast(float, ws[j2] & 0xFFFF0000u);
            }
        }
        const float sc = dot * scale;
        if (sc > m) {
            const float corr = __expf(m - sc);
            l *= corr;
            #pragma unroll
            for (int d = 0; d < 32; d++) o[d] *= corr;
            m = sc;
        }
        const float wgt = __expf(sc - m);
        l += wgt;
        const u16* vp = vT + base;
        #pragma unroll
        for (int i = 0; i < 4; i++) {
            uint4 wv = *(const uint4*)(vp + i * 8);
            u32 ws[4] = {wv.x, wv.y, wv.z, wv.w};
            #pragma unroll
            for (int j2 = 0; j2 < 4; j2++) {
                o[i*8 + 2*j2]     += wgt * __builtin_bit_cast(float, ws[j2] << 16);
                o[i*8 + 2*j2 + 1] += wgt * __builtin_bit_cast(float, ws[j2] & 0xFFFF0000u);
            }
        }
    }

    // merge 4 partial softmax states (butterfly across lanes part^1, part^2)
    #pragma unroll
    for (int dd = 1; dd <= 2; dd <<= 1) {
        const float mo  = __shfl_xor(m, dd, 64);
        const float lo2 = __shfl_xor(l, dd, 64);
        const float mn = fmaxf(m, mo);
        const float cs = __expf(m - mn);
        const float co = __expf(mo - mn);
        l = l * cs + lo2 * co;
        #pragma unroll
        for (int d = 0; d < 32; d++) {
            const float oo = __shfl_xor(o[d], dd, 64);
            o[d] = o[d] * cs + oo * co;
        }
        m = mn;
    }

    const float inv = 1.f / l;
    float os[8];
    if (part == 0) {
        #pragma unroll
        for (int j = 0; j < 8; j++) os[j] = o[j];
    } else if (part == 1) {
        #pragma unroll
        for (int j = 0; j < 8; j++) os[j] = o[8 + j];
    } else if (part == 2) {
        #pragma unroll
        for (int j = 0; j < 8; j++) os[j] = o[16 + j];
    } else {
        #pragma unroll
        for (int j = 0; j < 8; j++) os[j] = o[24 + j];
    }
    bf16x8 hv;
    #pragma unroll
    for (int j = 0; j < 8; j++) hv[j] = (short)f2bf(os[j] * inv);
    const int c = s_off + n * 32 + part * 8;
    *(bf16x8*)(fhi + sw_unit(p, c, 8) * 8) = hv;
}

__global__ __launch_bounds__(256) void attn_k(
    const u16* __restrict__ qT,
    const u16* __restrict__ k0T, const u16* __restrict__ v0T,
    const u16* __restrict__ k1T, const u16* __restrict__ v1T,
    u16* __restrict__ fhi)
{
    const int bx = blockIdx.x, t = threadIdx.x;
    const int s = bx >> 10;          // 0: win7/dil1/sf2 (mem 32x32), 1: win5/dil2/sf4 (16x16)
    const int r = bx & 1023;
    const int b = r >> 9, n = (r >> 6) & 7, qy = r & 63;
    const int qx = t >> 2, part = t & 3;
    if (s == 0) attn_one4<7, 1, 2, 32, 32>(qT, k0T, v0T, fhi, b, n, qy, qx, part, 0);
    else        attn_one4<5, 2, 4, 16, 16>(qT, k1T, v1T, fhi, b, n, qy, qx, part, 256);
}

// ---------------------------------------------------------------------------
extern "C" void kernel_launch(void* const* d_in, const int* in_sizes, int n_in,
                              void* d_out, int out_size, void* d_ws, size_t ws_size,
                              hipStream_t stream)
{
    const float* query = (const float*)d_in[0];
    const float* mem0  = (const float*)d_in[1];
    const float* mem1  = (const float*)d_in[2];
    const float* Wq    = (const float*)d_in[3];  const float* bq    = (const float*)d_in[4];
    const float* Wk0   = (const float*)d_in[5];  const float* bk0   = (const float*)d_in[6];
    const float* Wv0   = (const float*)d_in[7];  const float* bv0   = (const float*)d_in[8];
    const float* Wk1   = (const float*)d_in[9];  const float* bk1   = (const float*)d_in[10];
    const float* Wv1   = (const float*)d_in[11]; const float* bv1   = (const float*)d_in[12];
    const float* Wfuse = (const float*)d_in[13]; const float* bfuse = (const float*)d_in[14];
    float* out = (float*)d_out;

    // workspace layout (bytes) — q/k/v planes now bf16 (half of prior regions)
    char* ws = (char*)d_ws;
    u16* qT       = (u16*)(ws + 0);            // 4,194,304 used
    u16* k0T      = (u16*)(ws + 8388608);      // 1,048,576 used
    u16* v0T      = (u16*)(ws + 10485760);     // 1,048,576 used
    u16* k1T      = (u16*)(ws + 12582912);     //   262,144 used
    u16* v1T      = (u16*)(ws + 13107200);     //   262,144 used
    u16* Whi      = (u16*)(ws + 13631488);     // 1,572,864
    u16* Wlo      = (u16*)(ws + 15204352);     // 1,572,864
    u16* Xm0_hi   = (u16*)(ws + 16777216);     // 1,572,864
    u16* Xm0_lo   = (u16*)(ws + 18350080);     // 1,572,864
    u16* Xm1_hi   = (u16*)(ws + 19922944);     //   786,432
    u16* Xm1_lo   = (u16*)(ws + 20709376);     //   786,432
    u16* Xq_hi    = (u16*)(ws + 21495808);     // 4,194,304
    u16* Xq_lo    = (u16*)(ws + 25690112);     // 4,194,304
    // fused hi plane (8 MB) aliases Xq_hi+Xq_lo (dead after projmm_k)
    u16* fhi      = Xq_hi;

    prep_k<<<dim3(992), 256, 0, stream>>>(
        query, mem0, mem1, Wq, Wk0, Wv0, Wk1, Wv1, Wfuse,
        Xq_hi, Xq_lo, Xm0_hi, Xm0_lo, Xm1_hi, Xm1_lo, Whi, Wlo);

    projmm_k<<<dim3(208), 256, 0, stream>>>(
        Xq_hi, Xq_lo, Xm0_hi, Xm0_lo, Xm1_hi, Xm1_lo, Whi, Wlo,
        bq, bk0, bv0, bk1, bv1, qT, k0T, v0T, k1T, v1T);

    attn_k<<<dim3(2048), 256, 0, stream>>>(qT, k0T, v0T, k1T, v1T, fhi);

    fusemm_k<<<dim3(128), 256, 0, stream>>>(Whi, Wlo, fhi, bfuse, out);
}

// Round 6
// 67.665 us; speedup vs baseline: 1.7590x; 1.7590x over previous
//
#include <hip/hip_runtime.h>
#include <math.h>

typedef unsigned short u16;
typedef unsigned int u32;
typedef __attribute__((ext_vector_type(8))) short bf16x8;
typedef __attribute__((ext_vector_type(4))) float f32x4;

// ---------------- bf16 helpers (manual RNE; inputs are finite) ----------------
__device__ __forceinline__ u16 f2bf(float x) {
    u32 b = __builtin_bit_cast(u32, x);
    b += 0x7FFFu + ((b >> 16) & 1u);
    return (u16)(b >> 16);
}
__device__ __forceinline__ float bf2f(u16 u) {
    u32 b = ((u32)u) << 16;
    return __builtin_bit_cast(float, b);
}

// Swizzled tiled plane address, in 16-byte units.
// Plane layout: [row/128][c/64] tiles of 1024 units;
// unit-in-tile = (row&127)*8 + (slot ^ (row&7)), slot = (c&63)>>3.
__device__ __forceinline__ size_t sw_unit(int row, int c, int CC) {
    int slot = (c & 63) >> 3;
    return ((size_t)((row >> 7) * CC + (c >> 6)) << 10)
         + (size_t)((row & 127) << 3) + (size_t)(slot ^ (row & 7));
}

// ---------------------------------------------------------------------------
// prep: convert+transpose activations / convert weights into swizzled hi/lo
// bf16 planes.
// ---------------------------------------------------------------------------
__device__ void prep_x(const float* __restrict__ X, int C, int HW, int bl, int PT,
                       u16* __restrict__ dh, u16* __restrict__ dl) {
    __shared__ float Xt[64][65];
    const int t = threadIdx.x;
    const int pt = bl % PT, ct = bl / PT;
    const int p0 = pt * 64, c0 = ct * 64;
    const int b = p0 / HW, hw0 = p0 % HW;
    #pragma unroll
    for (int i = 0; i < 16; i++) {
        int r = (t >> 6) + i * 4;
        Xt[r][t & 63] = X[(size_t)(b * C + c0 + r) * HW + hw0 + (t & 63)];
    }
    __syncthreads();
    const int CC = C >> 6;
    #pragma unroll
    for (int it = 0; it < 2; it++) {
        int id = t + it * 256;
        int px = id >> 3, sl = id & 7;
        bf16x8 hv, lv;
        #pragma unroll
        for (int j = 0; j < 8; j++) {
            float x = Xt[sl * 8 + j][px];
            u16 h = f2bf(x);
            hv[j] = (short)h;
            lv[j] = (short)f2bf(x - bf2f(h));
        }
        size_t unit = sw_unit(p0 + px, c0 + sl * 8, CC);
        *(bf16x8*)(dh + unit * 8) = hv;
        *(bf16x8*)(dl + unit * 8) = lv;
    }
}

__device__ void prep_w(const float* __restrict__ W, int C, int bl,
                       u16* __restrict__ dh, u16* __restrict__ dl) {
    const int t = threadIdx.x;
    const int ot = bl & 3, cc = bl >> 2;
    const int o0 = ot * 64, c0 = cc * 64;
    const int CC = C >> 6;
    #pragma unroll
    for (int it = 0; it < 2; it++) {
        int id = t + it * 256;
        int ol = id >> 3, sl = id & 7;
        int o = o0 + ol, c = c0 + sl * 8;
        const float* wp = W + (size_t)o * C + c;
        float4 a = *(const float4*)wp;
        float4 b2 = *(const float4*)(wp + 4);
        float xs[8] = {a.x, a.y, a.z, a.w, b2.x, b2.y, b2.z, b2.w};
        bf16x8 hv, lv;
        #pragma unroll
        for (int j = 0; j < 8; j++) {
            u16 h = f2bf(xs[j]);
            hv[j] = (short)h;
            lv[j] = (short)f2bf(xs[j] - bf2f(h));
        }
        size_t unit = sw_unit(o, c, CC);
        *(bf16x8*)(dh + unit * 8) = hv;
        *(bf16x8*)(dl + unit * 8) = lv;
    }
}

// W plane offsets in u16 units inside the combined Whi/Wlo buffers
#define OFF_WQ 0
#define OFF_WK0 65536
#define OFF_WV0 163840
#define OFF_WK1 262144
#define OFF_WV1 458752
#define OFF_WFUSE 655360

__global__ __launch_bounds__(256) void prep_k(
    const float* __restrict__ query, const float* __restrict__ mem0, const float* __restrict__ mem1,
    const float* __restrict__ Wq, const float* __restrict__ Wk0, const float* __restrict__ Wv0,
    const float* __restrict__ Wk1, const float* __restrict__ Wv1, const float* __restrict__ Wfuse,
    u16* Xq_hi, u16* Xq_lo, u16* Xm0_hi, u16* Xm0_lo, u16* Xm1_hi, u16* Xm1_lo,
    u16* Whi, u16* Wlo)
{
    const int bx = blockIdx.x;
    if (bx < 512)      prep_x(query, 256, 4096, bx,       128, Xq_hi, Xq_lo);
    else if (bx < 704) prep_x(mem0,  384, 1024, bx - 512,  32, Xm0_hi, Xm0_lo);
    else if (bx < 800) prep_x(mem1,  768,  256, bx - 704,   8, Xm1_hi, Xm1_lo);
    else {
        int r = bx - 800;
        if (r < 16)       prep_w(Wq,    256, r,       Whi + OFF_WQ,    Wlo + OFF_WQ);
        else if (r < 40)  prep_w(Wk0,   384, r - 16,  Whi + OFF_WK0,   Wlo + OFF_WK0);
        else if (r < 64)  prep_w(Wv0,   384, r - 40,  Whi + OFF_WV0,   Wlo + OFF_WV0);
        else if (r < 112) prep_w(Wk1,   768, r - 64,  Whi + OFF_WK1,   Wlo + OFF_WK1);
        else if (r < 160) prep_w(Wv1,   768, r - 112, Whi + OFF_WV1,   Wlo + OFF_WV1);
        else              prep_w(Wfuse, 512, r - 160, Whi + OFF_WFUSE, Wlo + OFF_WFUSE);
    }
}

// ---------------------------------------------------------------------------
// Split-bf16 MFMA GEMM core (unchanged from R4, validated).
// ---------------------------------------------------------------------------
template<int BPL, bool OUT16>
__device__ __forceinline__ void gemm_core(
    const u16* __restrict__ Ahi, const u16* __restrict__ Alo,
    const u16* __restrict__ Bhi, const u16* __restrict__ Blo,
    const float* __restrict__ bias, void* __restrict__ Y,
    int CC, int am, int bn, u16* smem)
{
    constexpr int PL = 2 + BPL;
    const int t = threadIdx.x, lane = t & 63, w = t >> 6;
    const int wr = w >> 1, wc = w & 1;

    f32x4 acc[4][4];
    #pragma unroll
    for (int a = 0; a < 4; a++)
        #pragma unroll
        for (int b = 0; b < 4; b++)
            acc[a][b] = (f32x4){0.f, 0.f, 0.f, 0.f};

    for (int ck = 0; ck < CC; ck++) {
        const size_t aoff = ((size_t)(am * CC + ck)) << 13;
        const size_t boff = ((size_t)(bn * CC + ck)) << 13;
        bf16x8 stg[PL][4];
        #pragma unroll
        for (int it = 0; it < 4; it++) {
            const size_t o = (size_t)(t + it * 256) * 8;
            stg[0][it] = *(const bf16x8*)(Ahi + aoff + o);
            stg[1][it] = *(const bf16x8*)(Alo + aoff + o);
            stg[2][it] = *(const bf16x8*)(Bhi + boff + o);
            if (BPL == 2) stg[3][it] = *(const bf16x8*)(Blo + boff + o);
        }
        __syncthreads();
        #pragma unroll
        for (int p = 0; p < PL; p++)
            #pragma unroll
            for (int it = 0; it < 4; it++)
                *(bf16x8*)(smem + p * 8192 + (size_t)(t + it * 256) * 8) = stg[p][it];
        __syncthreads();

        #pragma unroll
        for (int kk = 0; kk < 2; kk++) {
            bf16x8 ah[4], al[4], bh[4], bl[4];
            #pragma unroll
            for (int tr = 0; tr < 4; tr++) {
                int row = wr * 64 + tr * 16 + (lane & 15);
                int off = row * 64 + (((kk * 4 + (lane >> 4)) ^ (row & 7)) << 3);
                ah[tr] = *(const bf16x8*)(smem + off);
                al[tr] = *(const bf16x8*)(smem + 8192 + off);
            }
            #pragma unroll
            for (int tc = 0; tc < 4; tc++) {
                int row = wc * 64 + tc * 16 + (lane & 15);
                int off = row * 64 + (((kk * 4 + (lane >> 4)) ^ (row & 7)) << 3);
                bh[tc] = *(const bf16x8*)(smem + 16384 + off);
                if (BPL == 2) bl[tc] = *(const bf16x8*)(smem + 24576 + off);
            }
            #pragma unroll
            for (int tr = 0; tr < 4; tr++)
                #pragma unroll
                for (int tc = 0; tc < 4; tc++) {
                    acc[tr][tc] = __builtin_amdgcn_mfma_f32_16x16x32_bf16(ah[tr], bh[tc], acc[tr][tc], 0, 0, 0);
                    acc[tr][tc] = __builtin_amdgcn_mfma_f32_16x16x32_bf16(al[tr], bh[tc], acc[tr][tc], 0, 0, 0);
                    if (BPL == 2)
                        acc[tr][tc] = __builtin_amdgcn_mfma_f32_16x16x32_bf16(ah[tr], bl[tc], acc[tr][tc], 0, 0, 0);
                }
        }
    }

    if (OUT16) {
        u16* Y16 = (u16*)Y;
        float bv[4];
        #pragma unroll
        for (int tc = 0; tc < 4; tc++)
            bv[tc] = bias[bn * 128 + wc * 64 + tc * 16 + (lane & 15)];
        #pragma unroll
        for (int tr = 0; tr < 4; tr++) {
            #pragma unroll
            for (int i = 0; i < 4; i++) {
                int rp = am * 128 + wr * 64 + tr * 16 + ((lane >> 4) << 2) + i;
                u16* yr = Y16 + (size_t)rp * 256 + bn * 128 + wc * 64 + (lane & 15);
                #pragma unroll
                for (int tc = 0; tc < 4; tc++)
                    yr[tc * 16] = f2bf(acc[tr][tc][i] + bv[tc]);
            }
        }
    } else {
        float* Yf = (float*)Y;
        #pragma unroll
        for (int tr = 0; tr < 4; tr++) {
            #pragma unroll
            for (int i = 0; i < 4; i++) {
                int o = am * 128 + wr * 64 + tr * 16 + ((lane >> 4) << 2) + i;
                float bv = bias[o];
                #pragma unroll
                for (int tc = 0; tc < 4; tc++) {
                    int pcol = bn * 128 + wc * 64 + tc * 16 + (lane & 15);
                    Yf[(size_t)((pcol >> 12) * 256 + o) * 4096 + (pcol & 4095)] = acc[tr][tc][i] + bv;
                }
            }
        }
    }
}

__global__ __launch_bounds__(256) void projmm_k(
    const u16* __restrict__ Xq_hi, const u16* __restrict__ Xq_lo,
    const u16* __restrict__ Xm0_hi, const u16* __restrict__ Xm0_lo,
    const u16* __restrict__ Xm1_hi, const u16* __restrict__ Xm1_lo,
    const u16* __restrict__ Whi, const u16* __restrict__ Wlo,
    const float* __restrict__ bq, const float* __restrict__ bk0, const float* __restrict__ bv0,
    const float* __restrict__ bk1, const float* __restrict__ bv1,
    u16* qT, u16* k0T, u16* v0T, u16* k1T, u16* v1T)
{
    __shared__ u16 smem[32768];
    const int bx = blockIdx.x;
    const u16 *Ah, *Al, *Bh, *Bl; const float* bias; u16* Y;
    int CC, am, bn;
    if (bx < 128) {
        am = bx >> 1; bn = bx & 1; CC = 4;
        Ah = Xq_hi; Al = Xq_lo; Bh = Whi + OFF_WQ; Bl = Wlo + OFF_WQ; bias = bq; Y = qT;
    } else if (bx < 192) {
        int r = bx - 128; am = r >> 2; int bnn = r & 3; CC = 6;
        Ah = Xm0_hi; Al = Xm0_lo;
        if (bnn < 2) { Bh = Whi + OFF_WK0; Bl = Wlo + OFF_WK0; bias = bk0; Y = k0T; bn = bnn; }
        else         { Bh = Whi + OFF_WV0; Bl = Wlo + OFF_WV0; bias = bv0; Y = v0T; bn = bnn - 2; }
    } else {
        int r = bx - 192; am = r >> 2; int bnn = r & 3; CC = 12;
        Ah = Xm1_hi; Al = Xm1_lo;
        if (bnn < 2) { Bh = Whi + OFF_WK1; Bl = Wlo + OFF_WK1; bias = bk1; Y = k1T; bn = bnn; }
        else         { Bh = Whi + OFF_WV1; Bl = Wlo + OFF_WV1; bias = bv1; Y = v1T; bn = bnn - 2; }
    }
    gemm_core<2, true>(Ah, Al, Bh, Bl, bias, (void*)Y, CC, am, bn, smem);
}

__global__ __launch_bounds__(256) void fusemm_k(
    const u16* __restrict__ Whi, const u16* __restrict__ Wlo,
    const u16* __restrict__ fhi, const float* __restrict__ bfuse, float* out)
{
    __shared__ u16 smem[24576];
    const int bx = blockIdx.x;
    gemm_core<1, false>(Whi + OFF_WFUSE, Wlo + OFF_WFUSE, fhi, (const u16*)nullptr,
                        bfuse, (void*)out, 8, bx & 1, bx >> 1, smem);
}

// ---------------------------------------------------------------------------
// MFMA attention. One wave per (b, head, 4x4 query tile).
// Candidate frame: 8x8 superset (cand = wy*8+wx).
//   SCALE=0: win7/dil1/sf2, 2x2 anchors; cand coarse = anchor0 - 3 + (wy,wx);
//            q-pixel r valid iff (wy,wx) within its anchor's 7x7 window.
//   SCALE=1: win5/dil2/sf4, single anchor; coarse = anchor + (wy-2)*2;
//            valid iff wy<5 && wx<5.
// Both + border mask. S = Q(16x32)·K(64x32)^T (4 MFMA), wave softmax,
// P->LDS bf16, O = P(16x64)·V(64x32) (4 MFMA), write swizzled fused plane.
// ---------------------------------------------------------------------------
template<int SCALE>
__device__ __forceinline__ void attn_mfma(
    const u16* __restrict__ qT, const u16* __restrict__ kT,
    const u16* __restrict__ vT, u16* __restrict__ fhi,
    int b, int n, int ty, int tx, int lane, u16* s_lds)
{
    constexpr int HM = SCALE ? 16 : 32;
    const int qy0 = ty * 4, qx0 = tx * 4;
    const int ay0 = SCALE ? (qy0 >> 2) : (qy0 >> 1);
    const int ax0 = SCALE ? (qx0 >> 2) : (qx0 >> 1);
    const int l15 = lane & 15, kg = lane >> 4;

    // ---- Q A-fragment: row = l15, k = kg*8 + j ----
    const int pA = (b * 64 + qy0 + (l15 >> 2)) * 64 + qx0 + (l15 & 3);
    const bf16x8 qf = *(const bf16x8*)(qT + (size_t)pA * 256 + n * 32 + kg * 8);

    // ---- S = Q·K^T over 4 candidate tiles ----
    f32x4 s[4];
    #pragma unroll
    for (int t = 0; t < 4; t++) {
        const int cand = t * 16 + l15;
        const int wy = cand >> 3, wx = cand & 7;
        const int my = SCALE ? (ay0 + (wy - 2) * 2) : (ay0 - 3 + wy);
        const int mx = SCALE ? (ax0 + (wx - 2) * 2) : (ax0 - 3 + wx);
        const int myc = min(max(my, 0), HM - 1), mxc = min(max(mx, 0), HM - 1);
        const bf16x8 kf = *(const bf16x8*)(kT + (size_t)((b * HM + myc) * HM + mxc) * 256 + n * 32 + kg * 8);
        s[t] = __builtin_amdgcn_mfma_f32_16x16x32_bf16(qf, kf, (f32x4){0.f, 0.f, 0.f, 0.f}, 0, 0, 0);
    }

    // ---- mask + scale.  D layout: row = kg*4+i, col(cand) = t*16+l15 ----
    const float scl = 0.17677669529663687f;
    float sv[4][4];
    #pragma unroll
    for (int t = 0; t < 4; t++) {
        const int cand = t * 16 + l15;
        const int wy = cand >> 3, wx = cand & 7;
        const int my = SCALE ? (ay0 + (wy - 2) * 2) : (ay0 - 3 + wy);
        const int mx = SCALE ? (ax0 + (wx - 2) * 2) : (ax0 - 3 + wx);
        const bool inb = (my >= 0) && (my < HM) && (mx >= 0) && (mx < HM);
        #pragma unroll
        for (int i = 0; i < 4; i++) {
            bool ok;
            if (SCALE) {
                ok = inb && (wy < 5) && (wx < 5);
            } else {
                const int r = kg * 4 + i;
                const int dy2 = (r >> 2) >> 1, dx2 = (r & 3) >> 1;
                ok = inb && ((u32)(wy - dy2) <= 6u) && ((u32)(wx - dx2) <= 6u);
            }
            sv[t][i] = ok ? s[t][i] * scl : -1e30f;
        }
    }

    // ---- softmax per row (reduce in-lane over t, then across 16 lanes) ----
    float linv[4];
    #pragma unroll
    for (int i = 0; i < 4; i++) {
        float m = fmaxf(fmaxf(sv[0][i], sv[1][i]), fmaxf(sv[2][i], sv[3][i]));
        #pragma unroll
        for (int dd = 1; dd < 16; dd <<= 1) m = fmaxf(m, __shfl_xor(m, dd, 64));
        float l = 0.f;
        #pragma unroll
        for (int t = 0; t < 4; t++) { sv[t][i] = __expf(sv[t][i] - m); l += sv[t][i]; }
        #pragma unroll
        for (int dd = 1; dd < 16; dd <<= 1) l += __shfl_xor(l, dd, 64);
        linv[i] = 1.f / l;
    }

    // ---- P -> LDS bf16 [16 rows][68 stride] ----
    #pragma unroll
    for (int t = 0; t < 4; t++)
        #pragma unroll
        for (int i = 0; i < 4; i++)
            s_lds[(kg * 4 + i) * 68 + t * 16 + l15] = f2bf(sv[t][i]);
    __syncthreads();   // all 4 waves same template path; drains LDS writes

    // ---- O = P·V  (A from LDS; B gathered: V[cand][ch]) ----
    f32x4 o[2] = {(f32x4){0.f,0.f,0.f,0.f}, (f32x4){0.f,0.f,0.f,0.f}};
    #pragma unroll
    for (int h = 0; h < 2; h++) {
        const bf16x8 pa = *(const bf16x8*)(s_lds + l15 * 68 + h * 32 + kg * 8);
        #pragma unroll
        for (int c = 0; c < 2; c++) {
            bf16x8 vf;
            #pragma unroll
            for (int j = 0; j < 8; j++) {
                const int cand = h * 32 + kg * 8 + j;
                const int wy = cand >> 3, wx = cand & 7;
                int my = SCALE ? (ay0 + (wy - 2) * 2) : (ay0 - 3 + wy);
                int mx = SCALE ? (ax0 + (wx - 2) * 2) : (ax0 - 3 + wx);
                my = min(max(my, 0), HM - 1); mx = min(max(mx, 0), HM - 1);
                vf[j] = (short)vT[(size_t)((b * HM + my) * HM + mx) * 256 + n * 32 + c * 16 + l15];
            }
            o[c] = __builtin_amdgcn_mfma_f32_16x16x32_bf16(pa, vf, o[c], 0, 0, 0);
        }
    }

    // ---- write O/l to swizzled fused plane ----
    #pragma unroll
    for (int c = 0; c < 2; c++) {
        #pragma unroll
        for (int i = 0; i < 4; i++) {
            const int r = kg * 4 + i;
            const int p = (b * 64 + qy0 + (r >> 2)) * 64 + qx0 + (r & 3);
            const int ch = (SCALE ? 256 : 0) + n * 32 + c * 16 + l15;
            fhi[sw_unit(p, ch, 8) * 8 + (ch & 7)] = f2bf(o[c][i] * linv[i]);
        }
    }
}

__global__ __launch_bounds__(256) void attn_k(
    const u16* __restrict__ qT,
    const u16* __restrict__ k0T, const u16* __restrict__ v0T,
    const u16* __restrict__ k1T, const u16* __restrict__ v1T,
    u16* __restrict__ fhi)
{
    __shared__ u16 s_lds[4][16 * 68];
    const int t = threadIdx.x, w = t >> 6, lane = t & 63;
    const int bx = blockIdx.x;
    const int sc = bx >> 10;                 // blocks [0,1024): scale0, [1024,2048): scale1
    const int tile = (bx & 1023) * 4 + w;    // (b, n, ty, tx)
    const int b = tile >> 11, n = (tile >> 8) & 7;
    const int ty = (tile >> 4) & 15, tx = tile & 15;
    if (sc == 0) attn_mfma<0>(qT, k0T, v0T, fhi, b, n, ty, tx, lane, s_lds[w]);
    else         attn_mfma<1>(qT, k1T, v1T, fhi, b, n, ty, tx, lane, s_lds[w]);
}

// ---------------------------------------------------------------------------
extern "C" void kernel_launch(void* const* d_in, const int* in_sizes, int n_in,
                              void* d_out, int out_size, void* d_ws, size_t ws_size,
                              hipStream_t stream)
{
    const float* query = (const float*)d_in[0];
    const float* mem0  = (const float*)d_in[1];
    const float* mem1  = (const float*)d_in[2];
    const float* Wq    = (const float*)d_in[3];  const float* bq    = (const float*)d_in[4];
    const float* Wk0   = (const float*)d_in[5];  const float* bk0   = (const float*)d_in[6];
    const float* Wv0   = (const float*)d_in[7];  const float* bv0   = (const float*)d_in[8];
    const float* Wk1   = (const float*)d_in[9];  const float* bk1   = (const float*)d_in[10];
    const float* Wv1   = (const float*)d_in[11]; const float* bv1   = (const float*)d_in[12];
    const float* Wfuse = (const float*)d_in[13]; const float* bfuse = (const float*)d_in[14];
    float* out = (float*)d_out;

    char* ws = (char*)d_ws;
    u16* qT       = (u16*)(ws + 0);            // 4 MB (bf16 pixel-major)
    u16* k0T      = (u16*)(ws + 8388608);      // 1 MB
    u16* v0T      = (u16*)(ws + 10485760);     // 1 MB
    u16* k1T      = (u16*)(ws + 12582912);     // 256 KB
    u16* v1T      = (u16*)(ws + 13107200);     // 256 KB
    u16* Whi      = (u16*)(ws + 13631488);
    u16* Wlo      = (u16*)(ws + 15204352);
    u16* Xm0_hi   = (u16*)(ws + 16777216);
    u16* Xm0_lo   = (u16*)(ws + 18350080);
    u16* Xm1_hi   = (u16*)(ws + 19922944);
    u16* Xm1_lo   = (u16*)(ws + 20709376);
    u16* Xq_hi    = (u16*)(ws + 21495808);     // 4 MB
    u16* Xq_lo    = (u16*)(ws + 25690112);     // 4 MB
    u16* fhi      = Xq_hi;                     // fused plane (8 MB) aliases Xq planes

    prep_k<<<dim3(992), 256, 0, stream>>>(
        query, mem0, mem1, Wq, Wk0, Wv0, Wk1, Wv1, Wfuse,
        Xq_hi, Xq_lo, Xm0_hi, Xm0_lo, Xm1_hi, Xm1_lo, Whi, Wlo);

    projmm_k<<<dim3(208), 256, 0, stream>>>(
        Xq_hi, Xq_lo, Xm0_hi, Xm0_lo, Xm1_hi, Xm1_lo, Whi, Wlo,
        bq, bk0, bv0, bk1, bv1, qT, k0T, v0T, k1T, v1T);

    attn_k<<<dim3(2048), 256, 0, stream>>>(qT, k0T, v0T, k1T, v1T, fhi);

    fusemm_k<<<dim3(128), 256, 0, stream>>>(Whi, Wlo, fhi, bfuse, out);
}